// Round 9
// baseline (267.749 us; speedup 1.0000x reference)
//
#include <hip/hip_runtime.h>
#include <hip/hip_bf16.h>
#include <cstdint>

// ---------------------------------------------------------------------------
// B=2, S=4096, D=512, H=8, HD=64.
// wt:   W -> W^T bf16, plain row-major [n][k].
// proj: fused QKV, 128x128 tiles, BK=32, 16 k-iters; X (fp32) staged via
//       register prefetch + cvt into XOR-swizzled LDS image; W^T staged via
//       global_load_lds with lane-side XOR (LDS image by construction);
//       XCD-pinned tile groups; LDS-staged coalesced image epilogue.
// attn: flash, S^T scheme, 32x32x16 MFMA, BARRIER-FREE K-loop: K/V fragments
//       loaded directly global->VGPR from the LDS-image buffers (identical
//       bytes/swizzle as the old LDS path); compiler pipelines loads with
//       vmcnt. 256-thr blocks (2 wq x 2 kh), grid 1024, 17KB merge LDS only.
//       V carries sigma(swap bits 2,3) key permutation so P's C-layout packing
//       IS the PV B-fragment (no cross-lane ops). No max-subtract softmax.
// ---------------------------------------------------------------------------

typedef __bf16   bf16x8 __attribute__((ext_vector_type(8)));
typedef _Float16 f16x8  __attribute__((ext_vector_type(8)));
typedef float    f32x4  __attribute__((ext_vector_type(4)));
typedef float    f32x16 __attribute__((ext_vector_type(16)));
typedef unsigned int   u32;
typedef unsigned int   u32x4 __attribute__((ext_vector_type(4)));
typedef unsigned short u16;

#define NB  2
#define SEQ 4096
#define DIM 512
#define NH  8
#define HD  64
#define WSZ (DIM * DIM)
#define QSZ (NB * NH * SEQ * HD)

__device__ __forceinline__ u16 f2bf(float f) {
    __bf16 h = (__bf16)f; return __builtin_bit_cast(u16, h);
}
__device__ __forceinline__ u16 f2h(float f) {
    _Float16 h = (_Float16)f; return __builtin_bit_cast(u16, h);
}
__device__ __forceinline__ u32 pack_pkrtz(float a, float b) {
    auto pk = __builtin_amdgcn_cvt_pkrtz(a, b);
    return __builtin_bit_cast(u32, pk);
}
__device__ __forceinline__ bf16x8 cvt8p(float4 a, float4 b) {
    bf16x8 o;
    o[0]=(__bf16)a.x; o[1]=(__bf16)a.y; o[2]=(__bf16)a.z; o[3]=(__bf16)a.w;
    o[4]=(__bf16)b.x; o[5]=(__bf16)b.y; o[6]=(__bf16)b.z; o[7]=(__bf16)b.w;
    return o;
}
__device__ __forceinline__ void dma16(const u16* g, u16* l) {
    __builtin_amdgcn_global_load_lds(
        (const __attribute__((address_space(1))) u32*)g,
        (__attribute__((address_space(3))) u32*)l, 16, 0, 0);
}

// --- W transpose: WT[p][n][k] = bf16(W_p[k][n]), row-major ------------------
__global__ __launch_bounds__(256) void wt_kernel(
    const float* __restrict__ Wq, const float* __restrict__ Wk,
    const float* __restrict__ Wv, u16* __restrict__ wt)
{
    __shared__ u16 lT[64 * 65];
    const int p = blockIdx.z;
    const float* W = (p == 0) ? Wq : ((p == 1) ? Wk : Wv);
    u16* dst = wt + (size_t)p * WSZ;
    const int r0 = blockIdx.x * 64, c0 = blockIdx.y * 64;
    const int t = threadIdx.x;
#pragma unroll
    for (int i = 0; i < 16; i++) {
        int idx = i * 256 + t, row = idx >> 6, col = idx & 63;
        lT[col * 65 + row] = f2bf(W[(size_t)(r0 + row) * DIM + c0 + col]);
    }
    __syncthreads();
#pragma unroll
    for (int i = 0; i < 16; i++) {
        int idx = i * 256 + t, n = idx >> 6, k = idx & 63;
        dst[(size_t)(c0 + n) * DIM + r0 + k] = lT[n * 65 + k];
    }
}

// --- fused projection -------------------------------------------------------
__global__ __launch_bounds__(256) void proj_kernel(
    const float* __restrict__ xq, const float* __restrict__ xk,
    const float* __restrict__ xv, const u16* __restrict__ wt,
    const float* __restrict__ bq, const float* __restrict__ bk,
    const float* __restrict__ bv,
    u16* __restrict__ qb, u16* __restrict__ kbImg, u16* __restrict__ vtImg)
{
    __shared__ u16 smem[16384];   // 2 buf x (4096 A | 4096 B); epilogue 32KB

    const int tid = threadIdx.x;
    const int wave = tid >> 6, lane = tid & 63;
    const int l16 = lane & 15, quad = lane >> 4;
    const int wq = wave >> 1, wn = wave & 1;

    // XCD pinning: id&7 = xcd; 96 blocks per XCD (32 per p)
    const int id = blockIdx.x;
    const int xcd = id & 7, j = id >> 3;
    const int p = j >> 5, t5 = j & 31;
    int mb, nb;
    if (p < 2) { mb = xcd * 8 + (t5 >> 2); nb = t5 & 3; }
    else       { nb = xcd * 8 + (t5 >> 2); mb = t5 & 3; }

    const float* Xp = (p == 0) ? xq : ((p == 1) ? xk : xv);
    const bool cvtA = (p < 2);
    const int xtile = cvtA ? mb : nb;           // X occupies A-half iff p<2
    const int wtile = cvtA ? nb : mb;
    const float* Xbase = Xp + (size_t)xtile * 128 * DIM;
    const u16*   Wbase = wt + (size_t)p * WSZ + (size_t)wtile * 128 * DIM;

    u16* ldsX0 = smem + (cvtA ? 0 : 4096);      // X half within a buffer
    u16* ldsW0 = smem + (cvtA ? 4096 : 0);

    // X staging role: thread -> (row, half)
    const int xrow = tid >> 1, xhalf = tid & 1;
    const int xsr = (xrow ^ (xrow >> 2)) & 3;
    const float* xsrc = Xbase + (size_t)xrow * DIM + xhalf * 16;
    const int xslot0 = xrow * 32 + (((xhalf * 2) ^ xsr) << 3);
    const int xslot1 = xrow * 32 + (((xhalf * 2 + 1) ^ xsr) << 3);

    // W DMA role: 2 chunks per thread
    int wslot[2]; const u16* wsrc[2];
#pragma unroll
    for (int e = 0; e < 2; e++) {
        const int flat = e * 256 + tid;
        const int row = flat >> 2, c = flat & 3;
        const int gc = c ^ ((row ^ (row >> 2)) & 3);
        wslot[e] = flat * 8;
        wsrc[e]  = Wbase + (size_t)row * DIM + gc * 8;
    }

    f32x4 acc[4][4];
#pragma unroll
    for (int ms = 0; ms < 4; ms++)
#pragma unroll
        for (int ns = 0; ns < 4; ns++)
#pragma unroll
            for (int jj = 0; jj < 4; jj++) acc[ms][ns][jj] = 0.f;

    // prologue: tile 0 into buf0
#pragma unroll
    for (int e = 0; e < 2; e++) dma16(wsrc[e], ldsW0 + wslot[e]);
    float4 rx0 = ((const float4*)xsrc)[0], rx1 = ((const float4*)xsrc)[1];
    float4 rx2 = ((const float4*)xsrc)[2], rx3 = ((const float4*)xsrc)[3];
    *(bf16x8*)(ldsX0 + xslot0) = cvt8p(rx0, rx1);
    *(bf16x8*)(ldsX0 + xslot1) = cvt8p(rx2, rx3);
    rx0 = ((const float4*)(xsrc + 32))[0]; rx1 = ((const float4*)(xsrc + 32))[1];
    rx2 = ((const float4*)(xsrc + 32))[2]; rx3 = ((const float4*)(xsrc + 32))[3];

    for (int kt = 0; kt < 16; kt++) {
        __syncthreads();                         // publish buf[kt&1]
        const int nxt = (kt + 1) & 1;
        if (kt < 15) {
#pragma unroll
            for (int e = 0; e < 2; e++)
                dma16(wsrc[e] + (kt + 1) * 32, ldsW0 + nxt * 8192 + wslot[e]);
            *(bf16x8*)(ldsX0 + nxt * 8192 + xslot0) = cvt8p(rx0, rx1);
            *(bf16x8*)(ldsX0 + nxt * 8192 + xslot1) = cvt8p(rx2, rx3);
        }
        if (kt < 14) {
            const float* s = xsrc + (kt + 2) * 32;
            rx0 = ((const float4*)s)[0]; rx1 = ((const float4*)s)[1];
            rx2 = ((const float4*)s)[2]; rx3 = ((const float4*)s)[3];
        }

        const u16* lA = smem + (kt & 1) * 8192;
        const u16* lB = lA + 4096;

        bf16x8 af[4];
#pragma unroll
        for (int ms = 0; ms < 4; ms++) {
            const int row = wq * 64 + ms * 16 + l16;
            const int sr = (row ^ (row >> 2)) & 3;
            af[ms] = *(const bf16x8*)&lA[row * 32 + ((quad ^ sr) << 3)];
        }
#pragma unroll
        for (int ns = 0; ns < 4; ns++) {
            const int rowb = wn * 64 + ns * 16 + l16;
            const int sb = (rowb ^ (rowb >> 2)) & 3;
            const bf16x8 b = *(const bf16x8*)&lB[rowb * 32 + ((quad ^ sb) << 3)];
#pragma unroll
            for (int ms = 0; ms < 4; ms++)
                acc[ms][ns] = __builtin_amdgcn_mfma_f32_16x16x32_bf16(af[ms], b, acc[ms][ns], 0, 0, 0);
        }
    }

    // ---- epilogue: stage tile in LDS in output-image order, dump linearly ---
    __syncthreads();
    if (p < 2) {
        const float* bias = p ? bk : bq;
        const float cs = (p == 0) ? 0.18033688011112042f : 1.0f;   // log2e/8
        const int stl = wn * 2 + wq;
        const int hh = nb * 2 + wn;
#pragma unroll
        for (int ns = 0; ns < 4; ns++) {
            const int ch = ns * 16 + l16;
            const float bval = bias[hh * 64 + ch];
#pragma unroll
            for (int ms = 0; ms < 4; ms++)
#pragma unroll
                for (int rr = 0; rr < 4; rr++) {
                    const int sqL = ms * 16 + quad * 4 + rr;
                    const float v = (acc[ms][ns][rr] + bval) * cs;
                    int off;
                    if (p == 0) off = sqL * 64 + ch;
                    else        off = sqL * 64 +
                                      (((ch >> 3) ^ ((sqL ^ (sqL >> 3)) & 7)) << 3) + (ch & 7);
                    smem[stl * 4096 + off] = f2bf(v);
                }
        }
    } else {
        const int stl = wq * 2 + wn;
#pragma unroll
        for (int ms = 0; ms < 4; ms++)
#pragma unroll
            for (int rr = 0; rr < 4; rr++) {
                const int hd = ms * 16 + quad * 4 + rr;
                const float bval = bv[mb * 128 + wq * 64 + hd];
                const int swh = (hd ^ (hd >> 3)) & 7;
#pragma unroll
                for (int ns = 0; ns < 4; ns++) {
                    const int nl = ns * 16 + l16;
                    const int sqpL = (nl & ~12) | ((nl & 8) >> 1) | ((nl & 4) << 1);
                    smem[stl * 4096 + hd * 64 +
                         (((sqpL >> 3) ^ swh) << 3) + (sqpL & 7)] =
                        f2h(acc[ms][ns][rr] + bval);
                }
            }
    }
    __syncthreads();

    {
        u16* dstp; size_t gbase;
        if (p < 2) {
            const int hh = nb * 2 + (wave >> 1);
            const int b2 = mb >> 5;
            const int row0 = (mb * 128 + (wave & 1) * 64) & 4095;
            if (p == 0) { dstp = qb;    gbase = ((size_t)(b2 * NH + hh) * 4096 + row0) * 64; }
            else        { dstp = kbImg; gbase = ((size_t)((b2 * NH + hh) * 64 + (row0 >> 6))) * 4096; }
        } else {
            const int hh = mb * 2 + (wave >> 1);
            const int b2 = nb >> 5;
            const int nblk = (nb & 31) * 2 + (wave & 1);
            dstp = vtImg; gbase = ((size_t)((b2 * NH + hh) * 64 + nblk)) * 4096;
        }
#pragma unroll
        for (int e = 0; e < 8; e++) {
            const u32x4 vv = *(const u32x4*)&smem[wave * 4096 + e * 512 + lane * 8];
            *(u32x4*)(dstp + gbase + e * 512 + lane * 8) = vv;
        }
    }
}

// --- flash attention: barrier-free K-loop, direct global->VGPR frags ---------
__global__ __launch_bounds__(256) void attn_kernel(
    const u16* __restrict__ qb, const u16* __restrict__ kbImg,
    const u16* __restrict__ vtImg, float* __restrict__ out)
{
    __shared__ float cmb[4224];   // 16 O-slots x 256 + 128 l  (~17KB)

    const int tid = threadIdx.x;
    const int wave = tid >> 6, lane = tid & 63;
    const int m31 = lane & 31, h = lane >> 5;
    const int wq = wave >> 1, kh = wave & 1;

    const int blk = blockIdx.x;
    const int xcd = blk & 7, idx = blk >> 3;     // idx 0..127
    const int bh = xcd * 2 + (idx >> 6);
    const int qt = idx & 63;
    const int qbase = qt * 64 + wq * 32;

    bf16x8 qF[4];
#pragma unroll
    for (int c = 0; c < 4; c++)
        qF[c] = *(const bf16x8*)(qb + ((size_t)bh * SEQ + qbase + m31) * HD + c * 16 + h * 8);

    // per-lane fragment offsets within an 8KB tile (u16 units)
    int koff[2][4], voff[2][2][2];
#pragma unroll
    for (int kg = 0; kg < 2; kg++) {
        const int rK = kg * 32 + m31;
        const int swK = (rK ^ (rK >> 3)) & 7;
#pragma unroll
        for (int c = 0; c < 4; c++)
            koff[kg][c] = (rK << 6) + (((2 * c + h) ^ swK) << 3);
#pragma unroll
        for (int c2 = 0; c2 < 2; c2++)
#pragma unroll
            for (int rv = 0; rv < 2; rv++) {
                const int row = rv * 32 + m31;
                const int swV = (row ^ (row >> 3)) & 7;
                voff[kg][c2][rv] = (row << 6) + (((4 * kg + 2 * c2 + h) ^ swV) << 3);
            }
    }

    const u16* kbase = kbImg + (size_t)(bh * 64 + kh * 32) * 4096;
    const u16* vbase = vtImg + (size_t)(bh * 64 + kh * 32) * 4096;

    f32x16 O0, O1;
#pragma unroll
    for (int j = 0; j < 16; j++) { O0[j] = 0.f; O1[j] = 0.f; }
    float l_acc = 0.f;

#pragma unroll 2
    for (int it = 0; it < 32; it++) {
#pragma unroll
        for (int kg = 0; kg < 2; kg++) {
            bf16x8 kA[4];
#pragma unroll
            for (int c = 0; c < 4; c++)
                kA[c] = *(const bf16x8*)(kbase + koff[kg][c]);
            f16x8 vA0[2], vA1[2];
#pragma unroll
            for (int c2 = 0; c2 < 2; c2++) {
                vA0[c2] = *(const f16x8*)(vbase + voff[kg][c2][0]);
                vA1[c2] = *(const f16x8*)(vbase + voff[kg][c2][1]);
            }

            f32x16 Sv;
#pragma unroll
            for (int j = 0; j < 16; j++) Sv[j] = 0.f;
#pragma unroll
            for (int c = 0; c < 4; c++)
                Sv = __builtin_amdgcn_mfma_f32_32x32x16_bf16(kA[c], qF[c], Sv, 0, 0, 0);

            float ps = 0.f;
            u32 P32[8];
#pragma unroll
            for (int mm = 0; mm < 8; mm++) {
                const float e0 = __builtin_amdgcn_exp2f(Sv[2 * mm]);
                const float e1 = __builtin_amdgcn_exp2f(Sv[2 * mm + 1]);
                ps += e0 + e1;
                P32[mm] = pack_pkrtz(e0, e1);
            }
            l_acc += ps;

            u32x4 f0, f1;
            f0[0] = P32[0]; f0[1] = P32[1]; f0[2] = P32[2]; f0[3] = P32[3];
            f1[0] = P32[4]; f1[1] = P32[5]; f1[2] = P32[6]; f1[3] = P32[7];
            const f16x8 pf0 = __builtin_bit_cast(f16x8, f0);
            const f16x8 pf1 = __builtin_bit_cast(f16x8, f1);
            O0 = __builtin_amdgcn_mfma_f32_32x32x16_f16(vA0[0], pf0, O0, 0, 0, 0);
            O0 = __builtin_amdgcn_mfma_f32_32x32x16_f16(vA0[1], pf1, O0, 0, 0, 0);
            O1 = __builtin_amdgcn_mfma_f32_32x32x16_f16(vA1[0], pf0, O1, 0, 0, 0);
            O1 = __builtin_amdgcn_mfma_f32_32x32x16_f16(vA1[1], pf1, O1, 0, 0, 0);
        }
        kbase += 4096;
        vbase += 4096;
    }

    // merge K-halves through LDS: kh=1 publishes, kh=0 combines + stores
    l_acc += __shfl_xor(l_acc, 32);
    if (kh == 1) {
#pragma unroll
        for (int hg = 0; hg < 2; hg++)
#pragma unroll
            for (int mm = 0; mm < 4; mm++) {
                f32x4 o;
#pragma unroll
                for (int j = 0; j < 4; j++) o[j] = (hg ? O1 : O0)[4 * mm + j];
                *(f32x4*)&cmb[(((wq * 2 + hg) * 4 + mm) << 8) + lane * 4] = o;
            }
        cmb[4096 + wq * 64 + lane] = l_acc;
    }
    __syncthreads();

    if (kh == 0) {
        const int b = bh >> 3, hcol = bh & 7;
        const float lt = l_acc + cmb[4096 + wq * 64 + lane];
        const float inv = 1.0f / lt;
        const int sq = qbase + m31;
#pragma unroll
        for (int hg = 0; hg < 2; hg++)
#pragma unroll
            for (int mm = 0; mm < 4; mm++) {
                const f32x4 po = *(const f32x4*)&cmb[(((wq * 2 + hg) * 4 + mm) << 8) + lane * 4];
                f32x4 o;
#pragma unroll
                for (int j = 0; j < 4; j++)
                    o[j] = ((hg ? O1 : O0)[4 * mm + j] + po[j]) * inv;
                *(f32x4*)&out[(((size_t)(b * SEQ + sq)) << 9) + hcol * 64
                              + hg * 32 + 8 * mm + 4 * h] = o;
            }
    }
}

// ---------------------------------------------------------------------------
extern "C" void kernel_launch(void* const* d_in, const int* in_sizes, int n_in,
                              void* d_out, int out_size, void* d_ws, size_t ws_size,
                              hipStream_t stream)
{
    const float* q  = (const float*)d_in[0];
    const float* k  = (const float*)d_in[1];
    const float* v  = (const float*)d_in[2];
    const float* Wq = (const float*)d_in[3];
    const float* bq = (const float*)d_in[4];
    const float* Wk = (const float*)d_in[5];
    const float* bk = (const float*)d_in[6];
    const float* Wv = (const float*)d_in[7];
    const float* bv = (const float*)d_in[8];
    float* out = (float*)d_out;

    // ws layout (u16): wt[3*WSZ] | qb[QSZ] | kbImg[QSZ] | vtImg[QSZ]
    u16* wt  = (u16*)d_ws;
    u16* qbp = wt  + (size_t)3 * WSZ;
    u16* kbp = qbp + (size_t)QSZ;
    u16* vtp = kbp + (size_t)QSZ;

    wt_kernel  <<<dim3(8, 8, 3), 256, 0, stream>>>(Wq, Wk, Wv, wt);
    proj_kernel<<<dim3(768),     256, 0, stream>>>(q, k, v, wt, bq, bk, bv,
                                                   qbp, kbp, vtp);
    attn_kernel<<<dim3(1024),    256, 0, stream>>>(qbp, kbp, vtp, out);
}

// Round 11
// 226.445 us; speedup vs baseline: 1.1824x; 1.1824x over previous
//
#include <hip/hip_runtime.h>
#include <hip/hip_bf16.h>
#include <cstdint>

// ---------------------------------------------------------------------------
// B=2, S=4096, D=512, H=8, HD=64.
// wt:   W -> W^T bf16, plain row-major [n][k].
// proj: fused QKV, 128x128 tiles, BK=32; X fp32 register-prefetch + cvt into
//       XOR-swizzled LDS image; W^T via global_load_lds with lane-side XOR;
//       XCD-pinned tile groups; LDS-staged coalesced image epilogue.
// attn: flash, S^T scheme, 32x32x16 MFMA, 512-thr blocks (4 wq x 2 kh).
//       48KB LDS: K double-buffered (2buf x 2kh x 8KB), V single-buffered
//       (2kh x 8KB) -> 3 blocks/CU = 6 waves/SIMD.
//       Two barriers/iter: A (prev LDS reads drained) -> issue K[it+1],V[it]
//       DMA -> QK+softmax from K[it] -> B (V[it] landed via issuing-wave
//       vmcnt(0)) -> PV. K/V L2-resident via XCD pinning.
//       Merge: O-slots occupy cmb floats 0..8191; l row at 8192+ (r10 bug:
//       l at 4096 collided with O-slot 16 -> 0.59 absmax).
// ---------------------------------------------------------------------------

typedef __bf16   bf16x8 __attribute__((ext_vector_type(8)));
typedef _Float16 f16x8  __attribute__((ext_vector_type(8)));
typedef float    f32x4  __attribute__((ext_vector_type(4)));
typedef float    f32x16 __attribute__((ext_vector_type(16)));
typedef unsigned int   u32;
typedef unsigned int   u32x4 __attribute__((ext_vector_type(4)));
typedef unsigned short u16;

#define NB  2
#define SEQ 4096
#define DIM 512
#define NH  8
#define HD  64
#define WSZ (DIM * DIM)
#define QSZ (NB * NH * SEQ * HD)

__device__ __forceinline__ u16 f2bf(float f) {
    __bf16 h = (__bf16)f; return __builtin_bit_cast(u16, h);
}
__device__ __forceinline__ u16 f2h(float f) {
    _Float16 h = (_Float16)f; return __builtin_bit_cast(u16, h);
}
__device__ __forceinline__ u32 pack_pkrtz(float a, float b) {
    auto pk = __builtin_amdgcn_cvt_pkrtz(a, b);
    return __builtin_bit_cast(u32, pk);
}
__device__ __forceinline__ bf16x8 cvt8p(float4 a, float4 b) {
    bf16x8 o;
    o[0]=(__bf16)a.x; o[1]=(__bf16)a.y; o[2]=(__bf16)a.z; o[3]=(__bf16)a.w;
    o[4]=(__bf16)b.x; o[5]=(__bf16)b.y; o[6]=(__bf16)b.z; o[7]=(__bf16)b.w;
    return o;
}
__device__ __forceinline__ void dma16(const u16* g, u16* l) {
    __builtin_amdgcn_global_load_lds(
        (const __attribute__((address_space(1))) u32*)g,
        (__attribute__((address_space(3))) u32*)l, 16, 0, 0);
}

// --- W transpose: WT[p][n][k] = bf16(W_p[k][n]), row-major ------------------
__global__ __launch_bounds__(256) void wt_kernel(
    const float* __restrict__ Wq, const float* __restrict__ Wk,
    const float* __restrict__ Wv, u16* __restrict__ wt)
{
    __shared__ u16 lT[64 * 65];
    const int p = blockIdx.z;
    const float* W = (p == 0) ? Wq : ((p == 1) ? Wk : Wv);
    u16* dst = wt + (size_t)p * WSZ;
    const int r0 = blockIdx.x * 64, c0 = blockIdx.y * 64;
    const int t = threadIdx.x;
#pragma unroll
    for (int i = 0; i < 16; i++) {
        int idx = i * 256 + t, row = idx >> 6, col = idx & 63;
        lT[col * 65 + row] = f2bf(W[(size_t)(r0 + row) * DIM + c0 + col]);
    }
    __syncthreads();
#pragma unroll
    for (int i = 0; i < 16; i++) {
        int idx = i * 256 + t, n = idx >> 6, k = idx & 63;
        dst[(size_t)(c0 + n) * DIM + r0 + k] = lT[n * 65 + k];
    }
}

// --- fused projection -------------------------------------------------------
__global__ __launch_bounds__(256) void proj_kernel(
    const float* __restrict__ xq, const float* __restrict__ xk,
    const float* __restrict__ xv, const u16* __restrict__ wt,
    const float* __restrict__ bq, const float* __restrict__ bk,
    const float* __restrict__ bv,
    u16* __restrict__ qb, u16* __restrict__ kbImg, u16* __restrict__ vtImg)
{
    __shared__ u16 smem[16384];   // 2 buf x (4096 A | 4096 B); epilogue 32KB

    const int tid = threadIdx.x;
    const int wave = tid >> 6, lane = tid & 63;
    const int l16 = lane & 15, quad = lane >> 4;
    const int wq = wave >> 1, wn = wave & 1;

    const int id = blockIdx.x;
    const int xcd = id & 7, j = id >> 3;
    const int p = j >> 5, t5 = j & 31;
    int mb, nb;
    if (p < 2) { mb = xcd * 8 + (t5 >> 2); nb = t5 & 3; }
    else       { nb = xcd * 8 + (t5 >> 2); mb = t5 & 3; }

    const float* Xp = (p == 0) ? xq : ((p == 1) ? xk : xv);
    const bool cvtA = (p < 2);
    const int xtile = cvtA ? mb : nb;
    const int wtile = cvtA ? nb : mb;
    const float* Xbase = Xp + (size_t)xtile * 128 * DIM;
    const u16*   Wbase = wt + (size_t)p * WSZ + (size_t)wtile * 128 * DIM;

    u16* ldsX0 = smem + (cvtA ? 0 : 4096);
    u16* ldsW0 = smem + (cvtA ? 4096 : 0);

    const int xrow = tid >> 1, xhalf = tid & 1;
    const int xsr = (xrow ^ (xrow >> 2)) & 3;
    const float* xsrc = Xbase + (size_t)xrow * DIM + xhalf * 16;
    const int xslot0 = xrow * 32 + (((xhalf * 2) ^ xsr) << 3);
    const int xslot1 = xrow * 32 + (((xhalf * 2 + 1) ^ xsr) << 3);

    int wslot[2]; const u16* wsrc[2];
#pragma unroll
    for (int e = 0; e < 2; e++) {
        const int flat = e * 256 + tid;
        const int row = flat >> 2, c = flat & 3;
        const int gc = c ^ ((row ^ (row >> 2)) & 3);
        wslot[e] = flat * 8;
        wsrc[e]  = Wbase + (size_t)row * DIM + gc * 8;
    }

    f32x4 acc[4][4];
#pragma unroll
    for (int ms = 0; ms < 4; ms++)
#pragma unroll
        for (int ns = 0; ns < 4; ns++)
#pragma unroll
            for (int jj = 0; jj < 4; jj++) acc[ms][ns][jj] = 0.f;

#pragma unroll
    for (int e = 0; e < 2; e++) dma16(wsrc[e], ldsW0 + wslot[e]);
    float4 rx0 = ((const float4*)xsrc)[0], rx1 = ((const float4*)xsrc)[1];
    float4 rx2 = ((const float4*)xsrc)[2], rx3 = ((const float4*)xsrc)[3];
    *(bf16x8*)(ldsX0 + xslot0) = cvt8p(rx0, rx1);
    *(bf16x8*)(ldsX0 + xslot1) = cvt8p(rx2, rx3);
    rx0 = ((const float4*)(xsrc + 32))[0]; rx1 = ((const float4*)(xsrc + 32))[1];
    rx2 = ((const float4*)(xsrc + 32))[2]; rx3 = ((const float4*)(xsrc + 32))[3];

    for (int kt = 0; kt < 16; kt++) {
        __syncthreads();
        const int nxt = (kt + 1) & 1;
        if (kt < 15) {
#pragma unroll
            for (int e = 0; e < 2; e++)
                dma16(wsrc[e] + (kt + 1) * 32, ldsW0 + nxt * 8192 + wslot[e]);
            *(bf16x8*)(ldsX0 + nxt * 8192 + xslot0) = cvt8p(rx0, rx1);
            *(bf16x8*)(ldsX0 + nxt * 8192 + xslot1) = cvt8p(rx2, rx3);
        }
        if (kt < 14) {
            const float* s = xsrc + (kt + 2) * 32;
            rx0 = ((const float4*)s)[0]; rx1 = ((const float4*)s)[1];
            rx2 = ((const float4*)s)[2]; rx3 = ((const float4*)s)[3];
        }

        const u16* lA = smem + (kt & 1) * 8192;
        const u16* lB = lA + 4096;

        bf16x8 af[4];
#pragma unroll
        for (int ms = 0; ms < 4; ms++) {
            const int row = wq * 64 + ms * 16 + l16;
            const int sr = (row ^ (row >> 2)) & 3;
            af[ms] = *(const bf16x8*)&lA[row * 32 + ((quad ^ sr) << 3)];
        }
#pragma unroll
        for (int ns = 0; ns < 4; ns++) {
            const int rowb = wn * 64 + ns * 16 + l16;
            const int sb = (rowb ^ (rowb >> 2)) & 3;
            const bf16x8 b = *(const bf16x8*)&lB[rowb * 32 + ((quad ^ sb) << 3)];
#pragma unroll
            for (int ms = 0; ms < 4; ms++)
                acc[ms][ns] = __builtin_amdgcn_mfma_f32_16x16x32_bf16(af[ms], b, acc[ms][ns], 0, 0, 0);
        }
    }

    __syncthreads();
    if (p < 2) {
        const float* bias = p ? bk : bq;
        const float cs = (p == 0) ? 0.18033688011112042f : 1.0f;   // log2e/8
        const int stl = wn * 2 + wq;
        const int hh = nb * 2 + wn;
#pragma unroll
        for (int ns = 0; ns < 4; ns++) {
            const int ch = ns * 16 + l16;
            const float bval = bias[hh * 64 + ch];
#pragma unroll
            for (int ms = 0; ms < 4; ms++)
#pragma unroll
                for (int rr = 0; rr < 4; rr++) {
                    const int sqL = ms * 16 + quad * 4 + rr;
                    const float v = (acc[ms][ns][rr] + bval) * cs;
                    int off;
                    if (p == 0) off = sqL * 64 + ch;
                    else        off = sqL * 64 +
                                      (((ch >> 3) ^ ((sqL ^ (sqL >> 3)) & 7)) << 3) + (ch & 7);
                    smem[stl * 4096 + off] = f2bf(v);
                }
        }
    } else {
        const int stl = wq * 2 + wn;
#pragma unroll
        for (int ms = 0; ms < 4; ms++)
#pragma unroll
            for (int rr = 0; rr < 4; rr++) {
                const int hd = ms * 16 + quad * 4 + rr;
                const float bval = bv[mb * 128 + wq * 64 + hd];
                const int swh = (hd ^ (hd >> 3)) & 7;
#pragma unroll
                for (int ns = 0; ns < 4; ns++) {
                    const int nl = ns * 16 + l16;
                    const int sqpL = (nl & ~12) | ((nl & 8) >> 1) | ((nl & 4) << 1);
                    smem[stl * 4096 + hd * 64 +
                         (((sqpL >> 3) ^ swh) << 3) + (sqpL & 7)] =
                        f2h(acc[ms][ns][rr] + bval);
                }
            }
    }
    __syncthreads();

    {
        u16* dstp; size_t gbase;
        if (p < 2) {
            const int hh = nb * 2 + (wave >> 1);
            const int b2 = mb >> 5;
            const int row0 = (mb * 128 + (wave & 1) * 64) & 4095;
            if (p == 0) { dstp = qb;    gbase = ((size_t)(b2 * NH + hh) * 4096 + row0) * 64; }
            else        { dstp = kbImg; gbase = ((size_t)((b2 * NH + hh) * 64 + (row0 >> 6))) * 4096; }
        } else {
            const int hh = mb * 2 + (wave >> 1);
            const int b2 = nb >> 5;
            const int nblk = (nb & 31) * 2 + (wave & 1);
            dstp = vtImg; gbase = ((size_t)((b2 * NH + hh) * 64 + nblk)) * 4096;
        }
#pragma unroll
        for (int e = 0; e < 8; e++) {
            const u32x4 vv = *(const u32x4*)&smem[wave * 4096 + e * 512 + lane * 8];
            *(u32x4*)(dstp + gbase + e * 512 + lane * 8) = vv;
        }
    }
}

// --- flash attention: 48KB LDS (K dbuf + V single), 2 barriers/iter ----------
__global__ __launch_bounds__(512) void attn_kernel(
    const u16* __restrict__ qb, const u16* __restrict__ kbImg,
    const u16* __restrict__ vtImg, float* __restrict__ out)
{
    __shared__ u16 smem[24576];   // K [2buf][2kh] 8KB each (32KB) | V [2kh] 8KB (16KB)
    float* cmb = (float*)smem;    // merge aliases smem after the loop

    const int tid = threadIdx.x;
    const int wave = tid >> 6, lane = tid & 63;
    const int m31 = lane & 31, h = lane >> 5;
    const int wq = wave >> 1, kh = wave & 1;

    const int blk = blockIdx.x;
    const int xcd = blk & 7, idx = blk >> 3;       // idx 0..63
    const int bh = xcd * 2 + (idx >> 5);
    const int qt = idx & 31;
    const int qbase = qt * 128 + wq * 32;

    bf16x8 qF[4];
#pragma unroll
    for (int c = 0; c < 4; c++)
        qF[c] = *(const bf16x8*)(qb + ((size_t)bh * SEQ + qbase + m31) * HD + c * 16 + h * 8);

    f32x16 O0, O1;
#pragma unroll
    for (int j = 0; j < 16; j++) { O0[j] = 0.f; O1[j] = 0.f; }
    float l_acc = 0.f;

    // DMA roles: waves 0-3 stage K, waves 4-7 stage V (both kh halves, hw halves)
    const int kv  = wave >> 2;          // 0 = K, 1 = V
    const int khT = (wave >> 1) & 1;
    const int hw  = wave & 1;
    const u16* img = kv ? vtImg : kbImg;
    const u16* gsrc = img + ((size_t)(bh * 64 + khT * 32)) * 4096 + hw * 2048 + lane * 8;
    u16* ldsK = smem;
    u16* ldsV = smem + 16384;

    // prologue: K[0] into buf 0
    if (kv == 0) {
        u16* dst = ldsK + khT * 4096 + hw * 2048 + lane * 8;
#pragma unroll
        for (int e = 0; e < 4; e++) dma16(gsrc + e * 512, dst + e * 512);
    }

    const int NT = 32;
    for (int it = 0; it < NT; it++) {
        __syncthreads();                               // A: K[it] landed, V free
        if (kv == 0) {
            if (it + 1 < NT) {
                u16* dst = ldsK + (((it + 1) & 1) * 2 + khT) * 4096 + hw * 2048 + lane * 8;
                const u16* src = gsrc + (size_t)(it + 1) * 4096;
#pragma unroll
                for (int e = 0; e < 4; e++) dma16(src + e * 512, dst + e * 512);
            }
        } else {
            u16* dst = ldsV + khT * 4096 + hw * 2048 + lane * 8;
            const u16* src = gsrc + (size_t)it * 4096;
#pragma unroll
            for (int e = 0; e < 4; e++) dma16(src + e * 512, dst + e * 512);
        }

        const u16* sK = ldsK + ((it & 1) * 2 + kh) * 4096;
        f16x8 pfs[2][2];
#pragma unroll
        for (int kg = 0; kg < 2; kg++) {
            const int rK = kg * 32 + m31;
            const int swK = (rK ^ (rK >> 3)) & 7;
            bf16x8 kA[4];
#pragma unroll
            for (int c = 0; c < 4; c++)
                kA[c] = *(const bf16x8*)&sK[(rK << 6) + (((2 * c + h) ^ swK) << 3)];

            f32x16 Sv;
#pragma unroll
            for (int j = 0; j < 16; j++) Sv[j] = 0.f;
#pragma unroll
            for (int c = 0; c < 4; c++)
                Sv = __builtin_amdgcn_mfma_f32_32x32x16_bf16(kA[c], qF[c], Sv, 0, 0, 0);

            float ps = 0.f;
            u32 P32[8];
#pragma unroll
            for (int mm = 0; mm < 8; mm++) {
                const float e0 = __builtin_amdgcn_exp2f(Sv[2 * mm]);
                const float e1 = __builtin_amdgcn_exp2f(Sv[2 * mm + 1]);
                ps += e0 + e1;
                P32[mm] = pack_pkrtz(e0, e1);
            }
            l_acc += ps;

            u32x4 f0, f1;
            f0[0] = P32[0]; f0[1] = P32[1]; f0[2] = P32[2]; f0[3] = P32[3];
            f1[0] = P32[4]; f1[1] = P32[5]; f1[2] = P32[6]; f1[3] = P32[7];
            pfs[kg][0] = __builtin_bit_cast(f16x8, f0);
            pfs[kg][1] = __builtin_bit_cast(f16x8, f1);
        }

        __syncthreads();                               // B: V[it] landed
        const u16* sV = ldsV + kh * 4096;
        const int swV0 = (m31 ^ (m31 >> 3)) & 7;
        const int rV1 = 32 + m31;
        const int swV1 = (rV1 ^ (rV1 >> 3)) & 7;
#pragma unroll
        for (int kg = 0; kg < 2; kg++) {
            f16x8 vA0[2], vA1[2];
#pragma unroll
            for (int c2 = 0; c2 < 2; c2++) {
                vA0[c2] = *(const f16x8*)&sV[(m31 << 6) + (((4 * kg + 2 * c2 + h) ^ swV0) << 3)];
                vA1[c2] = *(const f16x8*)&sV[(rV1 << 6) + (((4 * kg + 2 * c2 + h) ^ swV1) << 3)];
            }
            O0 = __builtin_amdgcn_mfma_f32_32x32x16_f16(vA0[0], pfs[kg][0], O0, 0, 0, 0);
            O0 = __builtin_amdgcn_mfma_f32_32x32x16_f16(vA0[1], pfs[kg][1], O0, 0, 0, 0);
            O1 = __builtin_amdgcn_mfma_f32_32x32x16_f16(vA1[0], pfs[kg][0], O1, 0, 0, 0);
            O1 = __builtin_amdgcn_mfma_f32_32x32x16_f16(vA1[1], pfs[kg][1], O1, 0, 0, 0);
        }
    }

    // merge the two K-halves through LDS.
    // O-slots: floats 0..8191 (32 slots x 256). l row: floats 8192..8447.
    l_acc += __shfl_xor(l_acc, 32);
    __syncthreads();
    if (kh == 1) {
#pragma unroll
        for (int hg = 0; hg < 2; hg++)
#pragma unroll
            for (int mm = 0; mm < 4; mm++) {
                f32x4 o;
#pragma unroll
                for (int j = 0; j < 4; j++) o[j] = (hg ? O1 : O0)[4 * mm + j];
                *(f32x4*)&cmb[(((wq * 2 + hg) * 4 + mm) << 8) + lane * 4] = o;
            }
        cmb[8192 + wq * 64 + lane] = l_acc;
    }
    __syncthreads();

    if (kh == 0) {
        const int b = bh >> 3, hcol = bh & 7;
        const float lt = l_acc + cmb[8192 + wq * 64 + lane];
        const float inv = 1.0f / lt;
        const int sq = qbase + m31;
#pragma unroll
        for (int hg = 0; hg < 2; hg++)
#pragma unroll
            for (int mm = 0; mm < 4; mm++) {
                const f32x4 po = *(const f32x4*)&cmb[(((wq * 2 + hg) * 4 + mm) << 8) + lane * 4];
                f32x4 o;
#pragma unroll
                for (int j = 0; j < 4; j++)
                    o[j] = ((hg ? O1 : O0)[4 * mm + j] + po[j]) * inv;
                *(f32x4*)&out[(((size_t)(b * SEQ + sq)) << 9) + hcol * 64
                              + hg * 32 + 8 * mm + 4 * h] = o;
            }
    }
}

// ---------------------------------------------------------------------------
extern "C" void kernel_launch(void* const* d_in, const int* in_sizes, int n_in,
                              void* d_out, int out_size, void* d_ws, size_t ws_size,
                              hipStream_t stream)
{
    const float* q  = (const float*)d_in[0];
    const float* k  = (const float*)d_in[1];
    const float* v  = (const float*)d_in[2];
    const float* Wq = (const float*)d_in[3];
    const float* bq = (const float*)d_in[4];
    const float* Wk = (const float*)d_in[5];
    const float* bk = (const float*)d_in[6];
    const float* Wv = (const float*)d_in[7];
    const float* bv = (const float*)d_in[8];
    float* out = (float*)d_out;

    // ws layout (u16): wt[3*WSZ] | qb[QSZ] | kbImg[QSZ] | vtImg[QSZ]
    u16* wt  = (u16*)d_ws;
    u16* qbp = wt  + (size_t)3 * WSZ;
    u16* kbp = qbp + (size_t)QSZ;
    u16* vtp = kbp + (size_t)QSZ;

    wt_kernel  <<<dim3(8, 8, 3), 256, 0, stream>>>(Wq, Wk, Wv, wt);
    proj_kernel<<<dim3(768),     256, 0, stream>>>(q, k, v, wt, bq, bk, bv,
                                                   qbp, kbp, vtp);
    attn_kernel<<<dim3(512),     512, 0, stream>>>(qbp, kbp, vtp, out);
}

// Round 12
// 219.102 us; speedup vs baseline: 1.2220x; 1.0335x over previous
//
#include <hip/hip_runtime.h>
#include <hip/hip_bf16.h>
#include <cstdint>

// ---------------------------------------------------------------------------
// B=2, S=4096, D=512, H=8, HD=64.
// wt:   W -> W^T bf16, plain row-major [n][k].
// proj: fused QKV, 128x128 tiles, BK=32; X fp32 register-prefetch + cvt into
//       XOR-swizzled LDS image; W^T via global_load_lds with lane-side XOR;
//       XCD-pinned tile groups; LDS-staged coalesced image epilogue.
// attn: flash, S^T scheme, 32x32x16 MFMA, 512-thr blocks (4 wq x 2 kh),
//       64KB LDS, K+V double-buffered, ONE barrier/iter (r8 structure = best
//       measured). New: (a) kg order staggered by wave parity so MFMA and
//       VALU bursts of different waves interleave instead of phase-locking;
//       (b) fragment offsets hoisted, P packed directly into B-operand regs.
//       V carries sigma(swap bits 2,3) key permutation so P's C-layout packing
//       IS the PV B-fragment. No max-subtract softmax (Q pre-scaled, base-2).
// ---------------------------------------------------------------------------

typedef __bf16   bf16x8 __attribute__((ext_vector_type(8)));
typedef _Float16 f16x8  __attribute__((ext_vector_type(8)));
typedef float    f32x4  __attribute__((ext_vector_type(4)));
typedef float    f32x16 __attribute__((ext_vector_type(16)));
typedef unsigned int   u32;
typedef unsigned int   u32x4 __attribute__((ext_vector_type(4)));
typedef unsigned short u16;

#define NB  2
#define SEQ 4096
#define DIM 512
#define NH  8
#define HD  64
#define WSZ (DIM * DIM)
#define QSZ (NB * NH * SEQ * HD)

__device__ __forceinline__ u16 f2bf(float f) {
    __bf16 h = (__bf16)f; return __builtin_bit_cast(u16, h);
}
__device__ __forceinline__ u16 f2h(float f) {
    _Float16 h = (_Float16)f; return __builtin_bit_cast(u16, h);
}
__device__ __forceinline__ u32 pack_pkrtz(float a, float b) {
    auto pk = __builtin_amdgcn_cvt_pkrtz(a, b);
    return __builtin_bit_cast(u32, pk);
}
__device__ __forceinline__ bf16x8 cvt8p(float4 a, float4 b) {
    bf16x8 o;
    o[0]=(__bf16)a.x; o[1]=(__bf16)a.y; o[2]=(__bf16)a.z; o[3]=(__bf16)a.w;
    o[4]=(__bf16)b.x; o[5]=(__bf16)b.y; o[6]=(__bf16)b.z; o[7]=(__bf16)b.w;
    return o;
}
__device__ __forceinline__ void dma16(const u16* g, u16* l) {
    __builtin_amdgcn_global_load_lds(
        (const __attribute__((address_space(1))) u32*)g,
        (__attribute__((address_space(3))) u32*)l, 16, 0, 0);
}

// --- W transpose: WT[p][n][k] = bf16(W_p[k][n]), row-major ------------------
__global__ __launch_bounds__(256) void wt_kernel(
    const float* __restrict__ Wq, const float* __restrict__ Wk,
    const float* __restrict__ Wv, u16* __restrict__ wt)
{
    __shared__ u16 lT[64 * 65];
    const int p = blockIdx.z;
    const float* W = (p == 0) ? Wq : ((p == 1) ? Wk : Wv);
    u16* dst = wt + (size_t)p * WSZ;
    const int r0 = blockIdx.x * 64, c0 = blockIdx.y * 64;
    const int t = threadIdx.x;
#pragma unroll
    for (int i = 0; i < 16; i++) {
        int idx = i * 256 + t, row = idx >> 6, col = idx & 63;
        lT[col * 65 + row] = f2bf(W[(size_t)(r0 + row) * DIM + c0 + col]);
    }
    __syncthreads();
#pragma unroll
    for (int i = 0; i < 16; i++) {
        int idx = i * 256 + t, n = idx >> 6, k = idx & 63;
        dst[(size_t)(c0 + n) * DIM + r0 + k] = lT[n * 65 + k];
    }
}

// --- fused projection -------------------------------------------------------
__global__ __launch_bounds__(256) void proj_kernel(
    const float* __restrict__ xq, const float* __restrict__ xk,
    const float* __restrict__ xv, const u16* __restrict__ wt,
    const float* __restrict__ bq, const float* __restrict__ bk,
    const float* __restrict__ bv,
    u16* __restrict__ qb, u16* __restrict__ kbImg, u16* __restrict__ vtImg)
{
    __shared__ u16 smem[16384];   // 2 buf x (4096 A | 4096 B); epilogue 32KB

    const int tid = threadIdx.x;
    const int wave = tid >> 6, lane = tid & 63;
    const int l16 = lane & 15, quad = lane >> 4;
    const int wq = wave >> 1, wn = wave & 1;

    const int id = blockIdx.x;
    const int xcd = id & 7, j = id >> 3;
    const int p = j >> 5, t5 = j & 31;
    int mb, nb;
    if (p < 2) { mb = xcd * 8 + (t5 >> 2); nb = t5 & 3; }
    else       { nb = xcd * 8 + (t5 >> 2); mb = t5 & 3; }

    const float* Xp = (p == 0) ? xq : ((p == 1) ? xk : xv);
    const bool cvtA = (p < 2);
    const int xtile = cvtA ? mb : nb;
    const int wtile = cvtA ? nb : mb;
    const float* Xbase = Xp + (size_t)xtile * 128 * DIM;
    const u16*   Wbase = wt + (size_t)p * WSZ + (size_t)wtile * 128 * DIM;

    u16* ldsX0 = smem + (cvtA ? 0 : 4096);
    u16* ldsW0 = smem + (cvtA ? 4096 : 0);

    const int xrow = tid >> 1, xhalf = tid & 1;
    const int xsr = (xrow ^ (xrow >> 2)) & 3;
    const float* xsrc = Xbase + (size_t)xrow * DIM + xhalf * 16;
    const int xslot0 = xrow * 32 + (((xhalf * 2) ^ xsr) << 3);
    const int xslot1 = xrow * 32 + (((xhalf * 2 + 1) ^ xsr) << 3);

    int wslot[2]; const u16* wsrc[2];
#pragma unroll
    for (int e = 0; e < 2; e++) {
        const int flat = e * 256 + tid;
        const int row = flat >> 2, c = flat & 3;
        const int gc = c ^ ((row ^ (row >> 2)) & 3);
        wslot[e] = flat * 8;
        wsrc[e]  = Wbase + (size_t)row * DIM + gc * 8;
    }

    f32x4 acc[4][4];
#pragma unroll
    for (int ms = 0; ms < 4; ms++)
#pragma unroll
        for (int ns = 0; ns < 4; ns++)
#pragma unroll
            for (int jj = 0; jj < 4; jj++) acc[ms][ns][jj] = 0.f;

#pragma unroll
    for (int e = 0; e < 2; e++) dma16(wsrc[e], ldsW0 + wslot[e]);
    float4 rx0 = ((const float4*)xsrc)[0], rx1 = ((const float4*)xsrc)[1];
    float4 rx2 = ((const float4*)xsrc)[2], rx3 = ((const float4*)xsrc)[3];
    *(bf16x8*)(ldsX0 + xslot0) = cvt8p(rx0, rx1);
    *(bf16x8*)(ldsX0 + xslot1) = cvt8p(rx2, rx3);
    rx0 = ((const float4*)(xsrc + 32))[0]; rx1 = ((const float4*)(xsrc + 32))[1];
    rx2 = ((const float4*)(xsrc + 32))[2]; rx3 = ((const float4*)(xsrc + 32))[3];

    for (int kt = 0; kt < 16; kt++) {
        __syncthreads();
        const int nxt = (kt + 1) & 1;
        if (kt < 15) {
#pragma unroll
            for (int e = 0; e < 2; e++)
                dma16(wsrc[e] + (kt + 1) * 32, ldsW0 + nxt * 8192 + wslot[e]);
            *(bf16x8*)(ldsX0 + nxt * 8192 + xslot0) = cvt8p(rx0, rx1);
            *(bf16x8*)(ldsX0 + nxt * 8192 + xslot1) = cvt8p(rx2, rx3);
        }
        if (kt < 14) {
            const float* s = xsrc + (kt + 2) * 32;
            rx0 = ((const float4*)s)[0]; rx1 = ((const float4*)s)[1];
            rx2 = ((const float4*)s)[2]; rx3 = ((const float4*)s)[3];
        }

        const u16* lA = smem + (kt & 1) * 8192;
        const u16* lB = lA + 4096;

        bf16x8 af[4];
#pragma unroll
        for (int ms = 0; ms < 4; ms++) {
            const int row = wq * 64 + ms * 16 + l16;
            const int sr = (row ^ (row >> 2)) & 3;
            af[ms] = *(const bf16x8*)&lA[row * 32 + ((quad ^ sr) << 3)];
        }
#pragma unroll
        for (int ns = 0; ns < 4; ns++) {
            const int rowb = wn * 64 + ns * 16 + l16;
            const int sb = (rowb ^ (rowb >> 2)) & 3;
            const bf16x8 b = *(const bf16x8*)&lB[rowb * 32 + ((quad ^ sb) << 3)];
#pragma unroll
            for (int ms = 0; ms < 4; ms++)
                acc[ms][ns] = __builtin_amdgcn_mfma_f32_16x16x32_bf16(af[ms], b, acc[ms][ns], 0, 0, 0);
        }
    }

    __syncthreads();
    if (p < 2) {
        const float* bias = p ? bk : bq;
        const float cs = (p == 0) ? 0.18033688011112042f : 1.0f;   // log2e/8
        const int stl = wn * 2 + wq;
        const int hh = nb * 2 + wn;
#pragma unroll
        for (int ns = 0; ns < 4; ns++) {
            const int ch = ns * 16 + l16;
            const float bval = bias[hh * 64 + ch];
#pragma unroll
            for (int ms = 0; ms < 4; ms++)
#pragma unroll
                for (int rr = 0; rr < 4; rr++) {
                    const int sqL = ms * 16 + quad * 4 + rr;
                    const float v = (acc[ms][ns][rr] + bval) * cs;
                    int off;
                    if (p == 0) off = sqL * 64 + ch;
                    else        off = sqL * 64 +
                                      (((ch >> 3) ^ ((sqL ^ (sqL >> 3)) & 7)) << 3) + (ch & 7);
                    smem[stl * 4096 + off] = f2bf(v);
                }
        }
    } else {
        const int stl = wq * 2 + wn;
#pragma unroll
        for (int ms = 0; ms < 4; ms++)
#pragma unroll
            for (int rr = 0; rr < 4; rr++) {
                const int hd = ms * 16 + quad * 4 + rr;
                const float bval = bv[mb * 128 + wq * 64 + hd];
                const int swh = (hd ^ (hd >> 3)) & 7;
#pragma unroll
                for (int ns = 0; ns < 4; ns++) {
                    const int nl = ns * 16 + l16;
                    const int sqpL = (nl & ~12) | ((nl & 8) >> 1) | ((nl & 4) << 1);
                    smem[stl * 4096 + hd * 64 +
                         (((sqpL >> 3) ^ swh) << 3) + (sqpL & 7)] =
                        f2h(acc[ms][ns][rr] + bval);
                }
            }
    }
    __syncthreads();

    {
        u16* dstp; size_t gbase;
        if (p < 2) {
            const int hh = nb * 2 + (wave >> 1);
            const int b2 = mb >> 5;
            const int row0 = (mb * 128 + (wave & 1) * 64) & 4095;
            if (p == 0) { dstp = qb;    gbase = ((size_t)(b2 * NH + hh) * 4096 + row0) * 64; }
            else        { dstp = kbImg; gbase = ((size_t)((b2 * NH + hh) * 64 + (row0 >> 6))) * 4096; }
        } else {
            const int hh = mb * 2 + (wave >> 1);
            const int b2 = nb >> 5;
            const int nblk = (nb & 31) * 2 + (wave & 1);
            dstp = vtImg; gbase = ((size_t)((b2 * NH + hh) * 64 + nblk)) * 4096;
        }
#pragma unroll
        for (int e = 0; e < 8; e++) {
            const u32x4 vv = *(const u32x4*)&smem[wave * 4096 + e * 512 + lane * 8];
            *(u32x4*)(dstp + gbase + e * 512 + lane * 8) = vv;
        }
    }
}

// --- flash attention: 64KB dbuf, 1 barrier/iter, wave-staggered kg -----------
__global__ __launch_bounds__(512) void attn_kernel(
    const u16* __restrict__ qb, const u16* __restrict__ kbImg,
    const u16* __restrict__ vtImg, float* __restrict__ out)
{
    __shared__ u16 smem[2 * 4 * 4096];   // [buf][kh*2+kv][8KB] = 64KB
    float* cmb = (float*)smem;

    const int tid = threadIdx.x;
    const int wave = tid >> 6, lane = tid & 63;
    const int m31 = lane & 31, h = lane >> 5;
    const int wq = wave >> 1, kh = wave & 1;

    const int blk = blockIdx.x;
    const int xcd = blk & 7, idx = blk >> 3;
    const int bh = xcd * 2 + (idx >> 5);
    const int qt = idx & 31;
    const int qbase = qt * 128 + wq * 32;

    bf16x8 qF[4];
#pragma unroll
    for (int c = 0; c < 4; c++)
        qF[c] = *(const bf16x8*)(qb + ((size_t)bh * SEQ + qbase + m31) * HD + c * 16 + h * 8);

    // hoisted fragment offsets (u16 units within an 8KB tile)
    int koff[2][4], voff[2][2][2];
#pragma unroll
    for (int kg = 0; kg < 2; kg++) {
        const int rK = kg * 32 + m31;
        const int swK = (rK ^ (rK >> 3)) & 7;
#pragma unroll
        for (int c = 0; c < 4; c++)
            koff[kg][c] = (rK << 6) + (((2 * c + h) ^ swK) << 3);
#pragma unroll
        for (int c2 = 0; c2 < 2; c2++)
#pragma unroll
            for (int rv = 0; rv < 2; rv++) {
                const int row = rv * 32 + m31;
                const int swV = (row ^ (row >> 3)) & 7;
                voff[kg][c2][rv] = (row << 6) + (((4 * kg + 2 * c2 + h) ^ swV) << 3);
            }
    }

    f32x16 O0, O1;
#pragma unroll
    for (int j = 0; j < 16; j++) { O0[j] = 0.f; O1[j] = 0.f; }
    float l_acc = 0.f;

    // DMA roles: wave pair stages one subtile; st = wave>>1 (khT, kv), hw half
    const int st = wave >> 1;
    const int hw = wave & 1;
    const u16* img = (st & 1) ? vtImg : kbImg;
    const u16* gp = img + ((size_t)(bh * 64 + (st >> 1) * 32)) * 4096 + hw * 2048 + lane * 8;
    {
        u16* lb = smem + st * 4096 + hw * 2048 + lane * 8;
#pragma unroll
        for (int e = 0; e < 4; e++) dma16(gp + e * 512, lb + e * 512);
        gp += 4096;
    }

    const int stag = wave & 1;           // kg traversal order parity
    const int NT = 32;
    for (int it = 0; it < NT; it++) {
        __syncthreads();
        if (it + 1 < NT) {
            u16* lb = smem + ((((it + 1) & 1) * 4 + st)) * 4096 + hw * 2048 + lane * 8;
#pragma unroll
            for (int e = 0; e < 4; e++) dma16(gp + e * 512, lb + e * 512);
            gp += 4096;
        }
        const u16* sK = smem + (size_t)(((it & 1) * 4) + kh * 2) * 4096;
        const u16* sV = sK + 4096;

#pragma unroll
        for (int kg_ = 0; kg_ < 2; kg_++) {
            const int kg = kg_ ^ stag;   // de-phase waves: half do kg 0,1; half 1,0
            bf16x8 kA[4];
#pragma unroll
            for (int c = 0; c < 4; c++)
                kA[c] = *(const bf16x8*)&sK[koff[kg][c]];
            f16x8 vA0[2], vA1[2];
#pragma unroll
            for (int c2 = 0; c2 < 2; c2++) {
                vA0[c2] = *(const f16x8*)&sV[voff[kg][c2][0]];
                vA1[c2] = *(const f16x8*)&sV[voff[kg][c2][1]];
            }

            f32x16 Sv;
#pragma unroll
            for (int j = 0; j < 16; j++) Sv[j] = 0.f;
#pragma unroll
            for (int c = 0; c < 4; c++)
                Sv = __builtin_amdgcn_mfma_f32_32x32x16_bf16(kA[c], qF[c], Sv, 0, 0, 0);

            float ps0 = 0.f, ps1 = 0.f;
            u32x4 f0, f1;
#pragma unroll
            for (int mm = 0; mm < 4; mm++) {
                const float e0 = __builtin_amdgcn_exp2f(Sv[2 * mm]);
                const float e1 = __builtin_amdgcn_exp2f(Sv[2 * mm + 1]);
                ps0 += e0; ps1 += e1;
                f0[mm] = pack_pkrtz(e0, e1);
            }
#pragma unroll
            for (int mm = 0; mm < 4; mm++) {
                const float e0 = __builtin_amdgcn_exp2f(Sv[8 + 2 * mm]);
                const float e1 = __builtin_amdgcn_exp2f(Sv[8 + 2 * mm + 1]);
                ps0 += e0; ps1 += e1;
                f1[mm] = pack_pkrtz(e0, e1);
            }
            l_acc += ps0 + ps1;

            const f16x8 pf0 = __builtin_bit_cast(f16x8, f0);
            const f16x8 pf1 = __builtin_bit_cast(f16x8, f1);
            O0 = __builtin_amdgcn_mfma_f32_32x32x16_f16(vA0[0], pf0, O0, 0, 0, 0);
            O0 = __builtin_amdgcn_mfma_f32_32x32x16_f16(vA0[1], pf1, O0, 0, 0, 0);
            O1 = __builtin_amdgcn_mfma_f32_32x32x16_f16(vA1[0], pf0, O1, 0, 0, 0);
            O1 = __builtin_amdgcn_mfma_f32_32x32x16_f16(vA1[1], pf1, O1, 0, 0, 0);
        }
    }

    // merge the two K-halves through LDS.
    // O-slots: cmb floats 0..8191 (32 slots x 256). l row: 8192..8447.
    l_acc += __shfl_xor(l_acc, 32);
    __syncthreads();
    if (kh == 1) {
#pragma unroll
        for (int hg = 0; hg < 2; hg++)
#pragma unroll
            for (int mm = 0; mm < 4; mm++) {
                f32x4 o;
#pragma unroll
                for (int j = 0; j < 4; j++) o[j] = (hg ? O1 : O0)[4 * mm + j];
                *(f32x4*)&cmb[(((wq * 2 + hg) * 4 + mm) << 8) + lane * 4] = o;
            }
        cmb[8192 + wq * 64 + lane] = l_acc;
    }
    __syncthreads();

    if (kh == 0) {
        const int b = bh >> 3, hcol = bh & 7;
        const float lt = l_acc + cmb[8192 + wq * 64 + lane];
        const float inv = 1.0f / lt;
        const int sq = qbase + m31;
#pragma unroll
        for (int hg = 0; hg < 2; hg++)
#pragma unroll
            for (int mm = 0; mm < 4; mm++) {
                const f32x4 po = *(const f32x4*)&cmb[(((wq * 2 + hg) * 4 + mm) << 8) + lane * 4];
                f32x4 o;
#pragma unroll
                for (int j = 0; j < 4; j++)
                    o[j] = ((hg ? O1 : O0)[4 * mm + j] + po[j]) * inv;
                *(f32x4*)&out[(((size_t)(b * SEQ + sq)) << 9) + hcol * 64
                              + hg * 32 + 8 * mm + 4 * h] = o;
            }
    }
}

// ---------------------------------------------------------------------------
extern "C" void kernel_launch(void* const* d_in, const int* in_sizes, int n_in,
                              void* d_out, int out_size, void* d_ws, size_t ws_size,
                              hipStream_t stream)
{
    const float* q  = (const float*)d_in[0];
    const float* k  = (const float*)d_in[1];
    const float* v  = (const float*)d_in[2];
    const float* Wq = (const float*)d_in[3];
    const float* bq = (const float*)d_in[4];
    const float* Wk = (const float*)d_in[5];
    const float* bk = (const float*)d_in[6];
    const float* Wv = (const float*)d_in[7];
    const float* bv = (const float*)d_in[8];
    float* out = (float*)d_out;

    // ws layout (u16): wt[3*WSZ] | qb[QSZ] | kbImg[QSZ] | vtImg[QSZ]
    u16* wt  = (u16*)d_ws;
    u16* qbp = wt  + (size_t)3 * WSZ;
    u16* kbp = qbp + (size_t)QSZ;
    u16* vtp = kbp + (size_t)QSZ;

    wt_kernel  <<<dim3(8, 8, 3), 256, 0, stream>>>(Wq, Wk, Wv, wt);
    proj_kernel<<<dim3(768),     256, 0, stream>>>(q, k, v, wt, bq, bk, bv,
                                                   qbp, kbp, vtp);
    attn_kernel<<<dim3(512),     512, 0, stream>>>(qbp, kbp, vtp, out);
}